// Round 3
// baseline (470.379 us; speedup 1.0000x reference)
//
#include <hip/hip_runtime.h>
#include <hip/hip_bf16.h>

#define TOK   16384
#define DIM   1024
#define INNER 4096
#define EPSF  1e-5f

typedef int v4i __attribute__((ext_vector_type(4)));

static __device__ __forceinline__ float bf2f(unsigned short u) {
    return __uint_as_float(((unsigned)u) << 16);
}
static __device__ __forceinline__ unsigned short f2bf(float f) {
    unsigned u = __float_as_uint(f);
    return (unsigned short)((u + 0x7fffu + ((u >> 16) & 1u)) >> 16);  // RNE
}

static __device__ __forceinline__ float waveSum(float v) {
#pragma unroll
    for (int o = 32; o > 0; o >>= 1) v += __shfl_down(v, o, 64);
    return v;
}
static __device__ __forceinline__ float waveMax(float v) {
#pragma unroll
    for (int o = 32; o > 0; o >>= 1) v = fmaxf(v, __shfl_down(v, o, 64));
    return v;
}

// ---- per-tensor sum(|w|) reduction (f32 in) ----
__global__ void absmean_k(const float* __restrict__ w, int n4, float* __restrict__ acc) {
    int idx = blockIdx.x * blockDim.x + threadIdx.x;
    int stride = gridDim.x * blockDim.x;
    const float4* w4 = (const float4*)w;
    float s = 0.f;
    for (int i = idx; i < n4; i += stride) {
        float4 v = w4[i];
        s += fabsf(v.x) + fabsf(v.y) + fabsf(v.z) + fabsf(v.w);
    }
    __shared__ float sp[4];
    int wv = threadIdx.x >> 6, lane = threadIdx.x & 63;
    s = waveSum(s);
    if (lane == 0) sp[wv] = s;
    __syncthreads();
    if (threadIdx.x == 0) atomicAdd(acc, sp[0] + sp[1] + sp[2] + sp[3]);
}

// ---- per-tensor ternary quantize: wq = clip(round(w/clip(mean|w|,eps)),-1,1) ----
__global__ void wquant_k(const float* __restrict__ w, int n,
                         const float* __restrict__ acc, float* __restrict__ wscale,
                         char* __restrict__ wq) {
    float mean = *acc / (float)n;
    float cl = fmaxf(mean, EPSF);
    float s = 1.f / cl;
    if (blockIdx.x == 0 && threadIdx.x == 0) *wscale = cl;  // dequant factor
    int idx = blockIdx.x * blockDim.x + threadIdx.x;
    int stride = gridDim.x * blockDim.x;
    int n4 = n >> 2;
    const float4* w4 = (const float4*)w;
    unsigned* q4 = (unsigned*)wq;
    for (int i = idx; i < n4; i += stride) {
        float4 v = w4[i];
        float e[4] = {v.x, v.y, v.z, v.w};
        unsigned packed = 0;
#pragma unroll
        for (int j = 0; j < 4; j++) {
            float r = rintf(e[j] * s);
            r = fminf(fmaxf(r, -1.f), 1.f);
            packed |= ((unsigned)((int)r & 0xff)) << (8 * j);
        }
        q4[i] = packed;
    }
}

// ---- RMSNorm + per-token absmax int8 quant, f32 input. One block per row. ----
template <int D, int VPT>
__global__ void actquant_f32_k(const float* __restrict__ X, char* __restrict__ Q,
                               float* __restrict__ rs_out) {
    int token = blockIdx.x;
    int t = threadIdx.x;
    const float4* xp = (const float4*)(X + (long)token * D);
    float vals[VPT];
    float ss = 0.f, am = 0.f;
#pragma unroll
    for (int j = 0; j < VPT / 4; j++) {
        float4 v = xp[t * (VPT / 4) + j];
        vals[4 * j] = v.x; vals[4 * j + 1] = v.y; vals[4 * j + 2] = v.z; vals[4 * j + 3] = v.w;
        ss += v.x * v.x + v.y * v.y + v.z * v.z + v.w * v.w;
        am = fmaxf(am, fmaxf(fmaxf(fabsf(v.x), fabsf(v.y)), fmaxf(fabsf(v.z), fabsf(v.w))));
    }
    __shared__ float sp[8];
    __shared__ float bc[2];
    int wv = t >> 6, lane = t & 63;
    float S = waveSum(ss);
    float M = waveMax(am);
    if (lane == 0) { sp[wv] = S; sp[4 + wv] = M; }
    __syncthreads();
    if (t == 0) {
        float Sa = sp[0] + sp[1] + sp[2] + sp[3];
        float Ma = fmaxf(fmaxf(sp[4], sp[5]), fmaxf(sp[6], sp[7]));
        float rinv = rsqrtf(Sa * (1.f / (float)D) + EPSF);   // rsqrt(mean(x^2)+eps)
        float amn = Ma * rinv;                                // absmax of normalized row
        float scale = 127.f / fmaxf(amn, EPSF);
        rs_out[token] = 1.f / scale;                          // dequant factor
        bc[0] = rinv; bc[1] = scale;
    }
    __syncthreads();
    float rinv = bc[0], scale = bc[1];
    unsigned outw[VPT / 4];
#pragma unroll
    for (int j = 0; j < VPT; j++) {
        float r = rintf((vals[j] * rinv) * scale);
        r = fminf(fmaxf(r, -128.f), 127.f);
        unsigned qi = (unsigned)((int)r & 0xff) << (8 * (j & 3));
        if ((j & 3) == 0) outw[j / 4] = qi; else outw[j / 4] |= qi;
    }
    unsigned* qp = (unsigned*)(Q + (long)token * D);
#pragma unroll
    for (int j = 0; j < VPT / 4; j++) qp[t * (VPT / 4) + j] = outw[j];
}

// ---- RMSNorm + int8 quant, bf16 input (for intermediate h). ----
template <int D, int VPT>
__global__ void actquant_bf16_k(const unsigned short* __restrict__ X, char* __restrict__ Q,
                                float* __restrict__ rs_out) {
    int token = blockIdx.x;
    int t = threadIdx.x;
    const unsigned* x2 = (const unsigned*)(X + (long)token * D);
    float vals[VPT];
    float ss = 0.f, am = 0.f;
#pragma unroll
    for (int j = 0; j < VPT / 2; j++) {
        unsigned v = x2[t * (VPT / 2) + j];
        float f0 = bf2f((unsigned short)(v & 0xffff));
        float f1 = bf2f((unsigned short)(v >> 16));
        vals[2 * j] = f0; vals[2 * j + 1] = f1;
        ss += f0 * f0 + f1 * f1;
        am = fmaxf(am, fmaxf(fabsf(f0), fabsf(f1)));
    }
    __shared__ float sp[8];
    __shared__ float bc[2];
    int wv = t >> 6, lane = t & 63;
    float S = waveSum(ss);
    float M = waveMax(am);
    if (lane == 0) { sp[wv] = S; sp[4 + wv] = M; }
    __syncthreads();
    if (t == 0) {
        float Sa = sp[0] + sp[1] + sp[2] + sp[3];
        float Ma = fmaxf(fmaxf(sp[4], sp[5]), fmaxf(sp[6], sp[7]));
        float rinv = rsqrtf(Sa * (1.f / (float)D) + EPSF);
        float amn = Ma * rinv;
        float scale = 127.f / fmaxf(amn, EPSF);
        rs_out[token] = 1.f / scale;
        bc[0] = rinv; bc[1] = scale;
    }
    __syncthreads();
    float rinv = bc[0], scale = bc[1];
    unsigned outw[VPT / 4];
#pragma unroll
    for (int j = 0; j < VPT; j++) {
        float r = rintf((vals[j] * rinv) * scale);
        r = fminf(fmaxf(r, -128.f), 127.f);
        unsigned qi = (unsigned)((int)r & 0xff) << (8 * (j & 3));
        if ((j & 3) == 0) outw[j / 4] = qi; else outw[j / 4] |= qi;
    }
    unsigned* qp = (unsigned*)(Q + (long)token * D);
#pragma unroll
    for (int j = 0; j < VPT / 4; j++) qp[t * (VPT / 4) + j] = outw[j];
}

// ---- int8 GEMM, 128x128 tile, BK=64 bytes, vanilla staging ----
// C[m,n] = sum_k A[m,k]*W[n,k]; epilogue: *rs[m]*wsc + bias[n]; optional erf-GELU
// OUT_F32: write float, else bf16. LDS rows padded 64->80B (2-way alias, free).
#define LDR 80
template <int DO_GELU, int OUT_F32>
__global__ __launch_bounds__(256) void gemm_i8_k(
    const char* __restrict__ A, const char* __restrict__ Bw,
    const float* __restrict__ rs, const float* __restrict__ wscale_p,
    const float* __restrict__ bias, void* __restrict__ outp,
    int M, int N, int K) {
    __shared__ char As[128 * LDR];
    __shared__ char Bs[128 * LDR];
    int t = threadIdx.x;
    int n0 = blockIdx.x * 128, m0 = blockIdx.y * 128;
    int wv = t >> 6, lane = t & 63, lm = lane & 15, q = lane >> 4;
    int wrow = (wv >> 1) * 64, wcol = (wv & 1) * 64;

    int r = t >> 2, c = t & 3;
    const uint4* Ap0 = (const uint4*)(A + (long)(m0 + r) * K + c * 16);
    const uint4* Ap1 = (const uint4*)(A + (long)(m0 + r + 64) * K + c * 16);
    const uint4* Bp0 = (const uint4*)(Bw + (long)(n0 + r) * K + c * 16);
    const uint4* Bp1 = (const uint4*)(Bw + (long)(n0 + r + 64) * K + c * 16);
    uint4* Asw0 = (uint4*)(As + r * LDR + c * 16);
    uint4* Asw1 = (uint4*)(As + (r + 64) * LDR + c * 16);
    uint4* Bsw0 = (uint4*)(Bs + r * LDR + c * 16);
    uint4* Bsw1 = (uint4*)(Bs + (r + 64) * LDR + c * 16);

    v4i acc[4][4] = {};
    const char* arow[4];
    const char* brow[4];
#pragma unroll
    for (int i = 0; i < 4; i++) {
        arow[i] = As + (wrow + i * 16 + lm) * LDR + q * 16;
        brow[i] = Bs + (wcol + i * 16 + lm) * LDR + q * 16;
    }

    for (int k0 = 0; k0 < K; k0 += 64) {
        int kc = k0 >> 4;
        uint4 a0 = Ap0[kc], a1 = Ap1[kc], b0 = Bp0[kc], b1 = Bp1[kc];
        __syncthreads();
        *Asw0 = a0; *Asw1 = a1; *Bsw0 = b0; *Bsw1 = b1;
        __syncthreads();
        v4i a[4], b[4];
#pragma unroll
        for (int i = 0; i < 4; i++) { a[i] = *(const v4i*)arow[i]; b[i] = *(const v4i*)brow[i]; }
#pragma unroll
        for (int i = 0; i < 4; i++)
#pragma unroll
            for (int j = 0; j < 4; j++)
                acc[i][j] = __builtin_amdgcn_mfma_i32_16x16x64_i8(a[i], b[j], acc[i][j], 0, 0, 0);
    }

    float wsc = *wscale_p;
#pragma unroll
    for (int i = 0; i < 4; i++) {
        int mg = m0 + wrow + i * 16 + q * 4;
        float fs[4];
#pragma unroll
        for (int rr = 0; rr < 4; rr++) fs[rr] = rs[mg + rr] * wsc;
#pragma unroll
        for (int j = 0; j < 4; j++) {
            int ng = n0 + wcol + j * 16 + lm;
            float bv = bias[ng];
#pragma unroll
            for (int rr = 0; rr < 4; rr++) {
                float v = (float)acc[i][j][rr] * fs[rr] + bv;
                if (DO_GELU) v = 0.5f * v * (1.f + erff(v * 0.70710678118654752f));
                long idx = (long)(mg + rr) * N + ng;
                if (OUT_F32) ((float*)outp)[idx] = v;
                else ((unsigned short*)outp)[idx] = f2bf(v);
            }
        }
    }
}

extern "C" void kernel_launch(void* const* d_in, const int* in_sizes, int n_in,
                              void* d_out, int out_size, void* d_ws, size_t ws_size,
                              hipStream_t stream) {
    const float* x  = (const float*)d_in[0];
    const float* w1 = (const float*)d_in[1];
    const float* b1 = (const float*)d_in[2];
    const float* w2 = (const float*)d_in[3];
    const float* b2 = (const float*)d_in[4];
    float* out = (float*)d_out;

    char* ws = (char*)d_ws;
    float* acc1 = (float*)(ws + 0);
    float* acc2 = (float*)(ws + 4);
    float* wsc1 = (float*)(ws + 8);
    float* wsc2 = (float*)(ws + 12);
    size_t off = 256;
    char* w1q = ws + off; off += (size_t)INNER * DIM;        // 4 MB
    char* w2q = ws + off; off += (size_t)INNER * DIM;        // 4 MB
    char* xq1 = ws + off; off += (size_t)TOK * DIM;          // 16 MB
    float* rs1 = (float*)(ws + off); off += (size_t)TOK * 4; // 64 KB
    char* xq2 = ws + off; off += (size_t)TOK * INNER;        // 64 MB
    float* rs2 = (float*)(ws + off); off += (size_t)TOK * 4; // 64 KB
    unsigned short* h = (unsigned short*)(ws + off);         // 128 MB bf16

    hipMemsetAsync(d_ws, 0, 16, stream);

    int nw = INNER * DIM;
    absmean_k<<<1024, 256, 0, stream>>>(w1, nw / 4, acc1);
    absmean_k<<<1024, 256, 0, stream>>>(w2, nw / 4, acc2);
    wquant_k<<<2048, 256, 0, stream>>>(w1, nw, acc1, wsc1, w1q);
    wquant_k<<<2048, 256, 0, stream>>>(w2, nw, acc2, wsc2, w2q);

    actquant_f32_k<DIM, 4><<<TOK, 256, 0, stream>>>(x, xq1, rs1);
    gemm_i8_k<1, 0><<<dim3(INNER / 128, TOK / 128), 256, 0, stream>>>(
        xq1, w1q, rs1, wsc1, b1, (void*)h, TOK, INNER, DIM);
    actquant_bf16_k<INNER, 16><<<TOK, 256, 0, stream>>>(h, xq2, rs2);
    gemm_i8_k<0, 1><<<dim3(DIM / 128, TOK / 128), 256, 0, stream>>>(
        xq2, w2q, rs2, wsc2, b2, (void*)out, TOK, DIM, INNER);
}

// Round 4
// 464.954 us; speedup vs baseline: 1.0117x; 1.0117x over previous
//
#include <hip/hip_runtime.h>
#include <hip/hip_bf16.h>

#define TOK   16384
#define DIM   1024
#define INNER 4096
#define EPSF  1e-5f

typedef int v4i __attribute__((ext_vector_type(4)));

static __device__ __forceinline__ void async_copy16(const char* g, char* l) {
    __builtin_amdgcn_global_load_lds(
        (const __attribute__((address_space(1))) unsigned int*)g,
        (__attribute__((address_space(3))) unsigned int*)l, 16, 0, 0);
}

static __device__ __forceinline__ float bf2f(unsigned short u) {
    return __uint_as_float(((unsigned)u) << 16);
}
static __device__ __forceinline__ unsigned short f2bf(float f) {
    unsigned u = __float_as_uint(f);
    return (unsigned short)((u + 0x7fffu + ((u >> 16) & 1u)) >> 16);  // RNE
}

static __device__ __forceinline__ float waveSum(float v) {
#pragma unroll
    for (int o = 32; o > 0; o >>= 1) v += __shfl_down(v, o, 64);
    return v;
}
static __device__ __forceinline__ float waveMax(float v) {
#pragma unroll
    for (int o = 32; o > 0; o >>= 1) v = fmaxf(v, __shfl_down(v, o, 64));
    return v;
}

// ---- per-tensor sum(|w|) reduction (f32 in) ----
__global__ void absmean_k(const float* __restrict__ w, int n4, float* __restrict__ acc) {
    int idx = blockIdx.x * blockDim.x + threadIdx.x;
    int stride = gridDim.x * blockDim.x;
    const float4* w4 = (const float4*)w;
    float s = 0.f;
    for (int i = idx; i < n4; i += stride) {
        float4 v = w4[i];
        s += fabsf(v.x) + fabsf(v.y) + fabsf(v.z) + fabsf(v.w);
    }
    __shared__ float sp[4];
    int wv = threadIdx.x >> 6, lane = threadIdx.x & 63;
    s = waveSum(s);
    if (lane == 0) sp[wv] = s;
    __syncthreads();
    if (threadIdx.x == 0) atomicAdd(acc, sp[0] + sp[1] + sp[2] + sp[3]);
}

// ---- per-tensor ternary quantize: wq = clip(round(w/clip(mean|w|,eps)),-1,1) ----
__global__ void wquant_k(const float* __restrict__ w, int n,
                         const float* __restrict__ acc, float* __restrict__ wscale,
                         char* __restrict__ wq) {
    float mean = *acc / (float)n;
    float cl = fmaxf(mean, EPSF);
    float s = 1.f / cl;
    if (blockIdx.x == 0 && threadIdx.x == 0) *wscale = cl;  // dequant factor
    int idx = blockIdx.x * blockDim.x + threadIdx.x;
    int stride = gridDim.x * blockDim.x;
    int n4 = n >> 2;
    const float4* w4 = (const float4*)w;
    unsigned* q4 = (unsigned*)wq;
    for (int i = idx; i < n4; i += stride) {
        float4 v = w4[i];
        float e[4] = {v.x, v.y, v.z, v.w};
        unsigned packed = 0;
#pragma unroll
        for (int j = 0; j < 4; j++) {
            float r = rintf(e[j] * s);
            r = fminf(fmaxf(r, -1.f), 1.f);
            packed |= ((unsigned)((int)r & 0xff)) << (8 * j);
        }
        q4[i] = packed;
    }
}

// ---- RMSNorm + per-token absmax int8 quant, f32 input. One block per row. ----
template <int D, int VPT>
__global__ void actquant_f32_k(const float* __restrict__ X, char* __restrict__ Q,
                               float* __restrict__ rs_out) {
    int token = blockIdx.x;
    int t = threadIdx.x;
    const float4* xp = (const float4*)(X + (long)token * D);
    float vals[VPT];
    float ss = 0.f, am = 0.f;
#pragma unroll
    for (int j = 0; j < VPT / 4; j++) {
        float4 v = xp[t * (VPT / 4) + j];
        vals[4 * j] = v.x; vals[4 * j + 1] = v.y; vals[4 * j + 2] = v.z; vals[4 * j + 3] = v.w;
        ss += v.x * v.x + v.y * v.y + v.z * v.z + v.w * v.w;
        am = fmaxf(am, fmaxf(fmaxf(fabsf(v.x), fabsf(v.y)), fmaxf(fabsf(v.z), fabsf(v.w))));
    }
    __shared__ float sp[8];
    __shared__ float bc[2];
    int wv = t >> 6, lane = t & 63;
    float S = waveSum(ss);
    float M = waveMax(am);
    if (lane == 0) { sp[wv] = S; sp[4 + wv] = M; }
    __syncthreads();
    if (t == 0) {
        float Sa = sp[0] + sp[1] + sp[2] + sp[3];
        float Ma = fmaxf(fmaxf(sp[4], sp[5]), fmaxf(sp[6], sp[7]));
        float rinv = rsqrtf(Sa * (1.f / (float)D) + EPSF);   // rsqrt(mean(x^2)+eps)
        float amn = Ma * rinv;                                // absmax of normalized row
        float scale = 127.f / fmaxf(amn, EPSF);
        rs_out[token] = 1.f / scale;                          // dequant factor
        bc[0] = rinv; bc[1] = scale;
    }
    __syncthreads();
    float rinv = bc[0], scale = bc[1];
    unsigned outw[VPT / 4];
#pragma unroll
    for (int j = 0; j < VPT; j++) {
        float r = rintf((vals[j] * rinv) * scale);
        r = fminf(fmaxf(r, -128.f), 127.f);
        unsigned qi = (unsigned)((int)r & 0xff) << (8 * (j & 3));
        if ((j & 3) == 0) outw[j / 4] = qi; else outw[j / 4] |= qi;
    }
    unsigned* qp = (unsigned*)(Q + (long)token * D);
#pragma unroll
    for (int j = 0; j < VPT / 4; j++) qp[t * (VPT / 4) + j] = outw[j];
}

// ---- RMSNorm + int8 quant, bf16 input (for intermediate h). ----
template <int D, int VPT>
__global__ void actquant_bf16_k(const unsigned short* __restrict__ X, char* __restrict__ Q,
                                float* __restrict__ rs_out) {
    int token = blockIdx.x;
    int t = threadIdx.x;
    const unsigned* x2 = (const unsigned*)(X + (long)token * D);
    float vals[VPT];
    float ss = 0.f, am = 0.f;
#pragma unroll
    for (int j = 0; j < VPT / 2; j++) {
        unsigned v = x2[t * (VPT / 2) + j];
        float f0 = bf2f((unsigned short)(v & 0xffff));
        float f1 = bf2f((unsigned short)(v >> 16));
        vals[2 * j] = f0; vals[2 * j + 1] = f1;
        ss += f0 * f0 + f1 * f1;
        am = fmaxf(am, fmaxf(fabsf(f0), fabsf(f1)));
    }
    __shared__ float sp[8];
    __shared__ float bc[2];
    int wv = t >> 6, lane = t & 63;
    float S = waveSum(ss);
    float M = waveMax(am);
    if (lane == 0) { sp[wv] = S; sp[4 + wv] = M; }
    __syncthreads();
    if (t == 0) {
        float Sa = sp[0] + sp[1] + sp[2] + sp[3];
        float Ma = fmaxf(fmaxf(sp[4], sp[5]), fmaxf(sp[6], sp[7]));
        float rinv = rsqrtf(Sa * (1.f / (float)D) + EPSF);
        float amn = Ma * rinv;
        float scale = 127.f / fmaxf(amn, EPSF);
        rs_out[token] = 1.f / scale;
        bc[0] = rinv; bc[1] = scale;
    }
    __syncthreads();
    float rinv = bc[0], scale = bc[1];
    unsigned outw[VPT / 4];
#pragma unroll
    for (int j = 0; j < VPT; j++) {
        float r = rintf((vals[j] * rinv) * scale);
        r = fminf(fmaxf(r, -128.f), 127.f);
        unsigned qi = (unsigned)((int)r & 0xff) << (8 * (j & 3));
        if ((j & 3) == 0) outw[j / 4] = qi; else outw[j / 4] |= qi;
    }
    unsigned* qp = (unsigned*)(Q + (long)token * D);
#pragma unroll
    for (int j = 0; j < VPT / 4; j++) qp[t * (VPT / 4) + j] = outw[j];
}

// ---- int8 GEMM, m97 structure: 128x128 tile, BK=64, global_load_lds(16B) ----
// C[m,n] = sum_k A[m,k]*W[n,k]; epilogue: *rs[m]*wsc + bias[n]; optional erf-GELU
// LDS unpadded (DMA requires lane-contiguous dest); XOR chunk swizzle (m97) for reads.
template <int DO_GELU, int OUT_F32>
__global__ __launch_bounds__(256) void gemm_i8_k(
    const char* __restrict__ A, const char* __restrict__ Bw,
    const float* __restrict__ rs, const float* __restrict__ wscale_p,
    const float* __restrict__ bias, void* __restrict__ outp,
    int M, int N, int K) {
    __shared__ char As[8192];
    __shared__ char Bs[8192];
    int t = threadIdx.x;
    int n0 = blockIdx.x * 128, m0 = blockIdx.y * 128;
    int wv = t >> 6, lane = t & 63, lm = lane & 15, q = lane >> 4;
    int wrow = (wv >> 1) * 64, wcol = (wv & 1) * 64;

    // staging: thread t covers LDS slot [t*16, t*16+16) => row r=t>>2, slot t&3
    // holds source chunk (t&3)^(r&3) (XOR swizzle to spread fragment-read banks)
    int r = t >> 2;
    int csrc = (t & 3) ^ (r & 3);
    const char* Ap = A + (long)(m0 + r) * K + csrc * 16;
    const char* Bp = Bw + (long)(n0 + r) * K + csrc * 16;
    long rowoff = (long)64 * K;

    v4i acc[4][4] = {};
    const v4i* As4 = (const v4i*)As;
    const v4i* Bs4 = (const v4i*)Bs;
    int aidx[4], bidx[4];
#pragma unroll
    for (int i = 0; i < 4; i++) {
        int ml = wrow + i * 16 + lm;
        aidx[i] = ml * 4 + (q ^ (ml & 3));
        int nl = wcol + i * 16 + lm;
        bidx[i] = nl * 4 + (q ^ (nl & 3));
    }

    for (int k0 = 0; k0 < K; k0 += 64) {
        async_copy16(Ap + k0,          As + t * 16);
        async_copy16(Ap + rowoff + k0, As + 4096 + t * 16);
        async_copy16(Bp + k0,          Bs + t * 16);
        async_copy16(Bp + rowoff + k0, Bs + 4096 + t * 16);
        __syncthreads();
        v4i a[4], b[4];
#pragma unroll
        for (int i = 0; i < 4; i++) { a[i] = As4[aidx[i]]; b[i] = Bs4[bidx[i]]; }
#pragma unroll
        for (int i = 0; i < 4; i++)
#pragma unroll
            for (int j = 0; j < 4; j++)
                acc[i][j] = __builtin_amdgcn_mfma_i32_16x16x64_i8(a[i], b[j], acc[i][j], 0, 0, 0);
        __syncthreads();
    }

    float wsc = *wscale_p;
#pragma unroll
    for (int i = 0; i < 4; i++) {
        int mg = m0 + wrow + i * 16 + q * 4;
        float fs[4];
#pragma unroll
        for (int rr = 0; rr < 4; rr++) fs[rr] = rs[mg + rr] * wsc;
#pragma unroll
        for (int j = 0; j < 4; j++) {
            int ng = n0 + wcol + j * 16 + lm;
            float bv = bias[ng];
#pragma unroll
            for (int rr = 0; rr < 4; rr++) {
                float v = (float)acc[i][j][rr] * fs[rr] + bv;
                if (DO_GELU) v = 0.5f * v * (1.f + erff(v * 0.70710678118654752f));
                long idx = (long)(mg + rr) * N + ng;
                if (OUT_F32) ((float*)outp)[idx] = v;
                else ((unsigned short*)outp)[idx] = f2bf(v);
            }
        }
    }
}

extern "C" void kernel_launch(void* const* d_in, const int* in_sizes, int n_in,
                              void* d_out, int out_size, void* d_ws, size_t ws_size,
                              hipStream_t stream) {
    const float* x  = (const float*)d_in[0];
    const float* w1 = (const float*)d_in[1];
    const float* b1 = (const float*)d_in[2];
    const float* w2 = (const float*)d_in[3];
    const float* b2 = (const float*)d_in[4];
    float* out = (float*)d_out;

    char* ws = (char*)d_ws;
    float* acc1 = (float*)(ws + 0);
    float* acc2 = (float*)(ws + 4);
    float* wsc1 = (float*)(ws + 8);
    float* wsc2 = (float*)(ws + 12);
    size_t off = 256;
    char* w1q = ws + off; off += (size_t)INNER * DIM;        // 4 MB
    char* w2q = ws + off; off += (size_t)INNER * DIM;        // 4 MB
    char* xq1 = ws + off; off += (size_t)TOK * DIM;          // 16 MB
    float* rs1 = (float*)(ws + off); off += (size_t)TOK * 4; // 64 KB
    char* xq2 = ws + off; off += (size_t)TOK * INNER;        // 64 MB
    float* rs2 = (float*)(ws + off); off += (size_t)TOK * 4; // 64 KB
    unsigned short* h = (unsigned short*)(ws + off);         // 128 MB bf16

    hipMemsetAsync(d_ws, 0, 16, stream);

    int nw = INNER * DIM;
    absmean_k<<<1024, 256, 0, stream>>>(w1, nw / 4, acc1);
    absmean_k<<<1024, 256, 0, stream>>>(w2, nw / 4, acc2);
    wquant_k<<<2048, 256, 0, stream>>>(w1, nw, acc1, wsc1, w1q);
    wquant_k<<<2048, 256, 0, stream>>>(w2, nw, acc2, wsc2, w2q);

    actquant_f32_k<DIM, 4><<<TOK, 256, 0, stream>>>(x, xq1, rs1);
    gemm_i8_k<1, 0><<<dim3(INNER / 128, TOK / 128), 256, 0, stream>>>(
        xq1, w1q, rs1, wsc1, b1, (void*)h, TOK, INNER, DIM);
    actquant_bf16_k<INNER, 16><<<TOK, 256, 0, stream>>>(h, xq2, rs2);
    gemm_i8_k<0, 1><<<dim3(DIM / 128, TOK / 128), 256, 0, stream>>>(
        xq2, w2q, rs2, wsc2, b2, (void*)out, TOK, DIM, INNER);
}

// Round 5
// 439.975 us; speedup vs baseline: 1.0691x; 1.0568x over previous
//
#include <hip/hip_runtime.h>
#include <hip/hip_bf16.h>

#define TOK   16384
#define DIM   1024
#define INNER 4096
#define EPSF  1e-5f

typedef int v4i __attribute__((ext_vector_type(4)));

static __device__ __forceinline__ void async_copy16(const char* g, char* l) {
    __builtin_amdgcn_global_load_lds(
        (const __attribute__((address_space(1))) unsigned int*)g,
        (__attribute__((address_space(3))) unsigned int*)l, 16, 0, 0);
}

static __device__ __forceinline__ float bf2f(unsigned short u) {
    return __uint_as_float(((unsigned)u) << 16);
}
static __device__ __forceinline__ unsigned short f2bf(float f) {
    unsigned u = __float_as_uint(f);
    return (unsigned short)((u + 0x7fffu + ((u >> 16) & 1u)) >> 16);  // RNE
}

// erf via Abramowitz-Stegun 7.1.26, |abs err| <= 1.5e-7 (vs libm erff ~50 VALU ops)
static __device__ __forceinline__ float fast_erf(float z) {
    float az = fabsf(z);
    float tt = __builtin_amdgcn_rcpf(1.f + 0.3275911f * az);
    float poly = ((((1.061405429f * tt - 1.453152027f) * tt + 1.421413741f) * tt
                   - 0.284496736f) * tt + 0.254829592f) * tt;
    float er = 1.f - poly * __expf(-az * az);
    return copysignf(er, z);
}

static __device__ __forceinline__ float waveSum(float v) {
#pragma unroll
    for (int o = 32; o > 0; o >>= 1) v += __shfl_down(v, o, 64);
    return v;
}
static __device__ __forceinline__ float waveMax(float v) {
#pragma unroll
    for (int o = 32; o > 0; o >>= 1) v = fmaxf(v, __shfl_down(v, o, 64));
    return v;
}

// ---- per-tensor sum(|w|) reduction (f32 in) ----
__global__ void absmean_k(const float* __restrict__ w, int n4, float* __restrict__ acc) {
    int idx = blockIdx.x * blockDim.x + threadIdx.x;
    int stride = gridDim.x * blockDim.x;
    const float4* w4 = (const float4*)w;
    float s = 0.f;
    for (int i = idx; i < n4; i += stride) {
        float4 v = w4[i];
        s += fabsf(v.x) + fabsf(v.y) + fabsf(v.z) + fabsf(v.w);
    }
    __shared__ float sp[4];
    int wv = threadIdx.x >> 6, lane = threadIdx.x & 63;
    s = waveSum(s);
    if (lane == 0) sp[wv] = s;
    __syncthreads();
    if (threadIdx.x == 0) atomicAdd(acc, sp[0] + sp[1] + sp[2] + sp[3]);
}

// ---- per-tensor ternary quantize: wq = clip(round(w/clip(mean|w|,eps)),-1,1) ----
__global__ void wquant_k(const float* __restrict__ w, int n,
                         const float* __restrict__ acc, float* __restrict__ wscale,
                         char* __restrict__ wq) {
    float mean = *acc / (float)n;
    float cl = fmaxf(mean, EPSF);
    float s = 1.f / cl;
    if (blockIdx.x == 0 && threadIdx.x == 0) *wscale = cl;  // dequant factor
    int idx = blockIdx.x * blockDim.x + threadIdx.x;
    int stride = gridDim.x * blockDim.x;
    int n4 = n >> 2;
    const float4* w4 = (const float4*)w;
    unsigned* q4 = (unsigned*)wq;
    for (int i = idx; i < n4; i += stride) {
        float4 v = w4[i];
        float e[4] = {v.x, v.y, v.z, v.w};
        unsigned packed = 0;
#pragma unroll
        for (int j = 0; j < 4; j++) {
            float r = rintf(e[j] * s);
            r = fminf(fmaxf(r, -1.f), 1.f);
            packed |= ((unsigned)((int)r & 0xff)) << (8 * j);
        }
        q4[i] = packed;
    }
}

// ---- RMSNorm + per-token absmax int8 quant, f32 input. One block per row. ----
template <int D, int VPT>
__global__ void actquant_f32_k(const float* __restrict__ X, char* __restrict__ Q,
                               float* __restrict__ rs_out) {
    int token = blockIdx.x;
    int t = threadIdx.x;
    const float4* xp = (const float4*)(X + (long)token * D);
    float vals[VPT];
    float ss = 0.f, am = 0.f;
#pragma unroll
    for (int j = 0; j < VPT / 4; j++) {
        float4 v = xp[t * (VPT / 4) + j];
        vals[4 * j] = v.x; vals[4 * j + 1] = v.y; vals[4 * j + 2] = v.z; vals[4 * j + 3] = v.w;
        ss += v.x * v.x + v.y * v.y + v.z * v.z + v.w * v.w;
        am = fmaxf(am, fmaxf(fmaxf(fabsf(v.x), fabsf(v.y)), fmaxf(fabsf(v.z), fabsf(v.w))));
    }
    __shared__ float sp[8];
    __shared__ float bc[2];
    int wv = t >> 6, lane = t & 63;
    float S = waveSum(ss);
    float M = waveMax(am);
    if (lane == 0) { sp[wv] = S; sp[4 + wv] = M; }
    __syncthreads();
    if (t == 0) {
        float Sa = sp[0] + sp[1] + sp[2] + sp[3];
        float Ma = fmaxf(fmaxf(sp[4], sp[5]), fmaxf(sp[6], sp[7]));
        float rinv = rsqrtf(Sa * (1.f / (float)D) + EPSF);   // rsqrt(mean(x^2)+eps)
        float amn = Ma * rinv;                                // absmax of normalized row
        float scale = 127.f / fmaxf(amn, EPSF);
        rs_out[token] = 1.f / scale;                          // dequant factor
        bc[0] = rinv; bc[1] = scale;
    }
    __syncthreads();
    float rinv = bc[0], scale = bc[1];
    unsigned outw[VPT / 4];
#pragma unroll
    for (int j = 0; j < VPT; j++) {
        float r = rintf((vals[j] * rinv) * scale);
        r = fminf(fmaxf(r, -128.f), 127.f);
        unsigned qi = (unsigned)((int)r & 0xff) << (8 * (j & 3));
        if ((j & 3) == 0) outw[j / 4] = qi; else outw[j / 4] |= qi;
    }
    unsigned* qp = (unsigned*)(Q + (long)token * D);
#pragma unroll
    for (int j = 0; j < VPT / 4; j++) qp[t * (VPT / 4) + j] = outw[j];
}

// ---- RMSNorm + int8 quant, bf16 input (for intermediate h). ----
template <int D, int VPT>
__global__ void actquant_bf16_k(const unsigned short* __restrict__ X, char* __restrict__ Q,
                                float* __restrict__ rs_out) {
    int token = blockIdx.x;
    int t = threadIdx.x;
    const unsigned* x2 = (const unsigned*)(X + (long)token * D);
    float vals[VPT];
    float ss = 0.f, am = 0.f;
#pragma unroll
    for (int j = 0; j < VPT / 2; j++) {
        unsigned v = x2[t * (VPT / 2) + j];
        float f0 = bf2f((unsigned short)(v & 0xffff));
        float f1 = bf2f((unsigned short)(v >> 16));
        vals[2 * j] = f0; vals[2 * j + 1] = f1;
        ss += f0 * f0 + f1 * f1;
        am = fmaxf(am, fmaxf(fabsf(f0), fabsf(f1)));
    }
    __shared__ float sp[8];
    __shared__ float bc[2];
    int wv = t >> 6, lane = t & 63;
    float S = waveSum(ss);
    float M = waveMax(am);
    if (lane == 0) { sp[wv] = S; sp[4 + wv] = M; }
    __syncthreads();
    if (t == 0) {
        float Sa = sp[0] + sp[1] + sp[2] + sp[3];
        float Ma = fmaxf(fmaxf(sp[4], sp[5]), fmaxf(sp[6], sp[7]));
        float rinv = rsqrtf(Sa * (1.f / (float)D) + EPSF);
        float amn = Ma * rinv;
        float scale = 127.f / fmaxf(amn, EPSF);
        rs_out[token] = 1.f / scale;
        bc[0] = rinv; bc[1] = scale;
    }
    __syncthreads();
    float rinv = bc[0], scale = bc[1];
    unsigned outw[VPT / 4];
#pragma unroll
    for (int j = 0; j < VPT; j++) {
        float r = rintf((vals[j] * rinv) * scale);
        r = fminf(fmaxf(r, -128.f), 127.f);
        unsigned qi = (unsigned)((int)r & 0xff) << (8 * (j & 3));
        if ((j & 3) == 0) outw[j / 4] = qi; else outw[j / 4] |= qi;
    }
    unsigned* qp = (unsigned*)(Q + (long)token * D);
#pragma unroll
    for (int j = 0; j < VPT / 4; j++) qp[t * (VPT / 4) + j] = outw[j];
}

// ---- int8 GEMM: 128x128 tile, BK=64, global_load_lds(16B), DOUBLE-BUFFERED ----
// Software pipeline with raw s_barrier + fine vmcnt(4): tile k+1's DMA stays in
// flight across the barriers while tile k computes (AITER-style, no full drain).
// C[m,n] = sum_k A[m,k]*W[n,k]; epilogue: *rs[m]*wsc + bias[n]; opt fast-erf GELU.
template <int DO_GELU, int OUT_F32>
__global__ __launch_bounds__(256) void gemm_i8_k(
    const char* __restrict__ A, const char* __restrict__ Bw,
    const float* __restrict__ rs, const float* __restrict__ wscale_p,
    const float* __restrict__ bias, void* __restrict__ outp,
    int M, int N, int K) {
    __shared__ char As[2][8192];
    __shared__ char Bs[2][8192];
    int t = threadIdx.x;
    int n0 = blockIdx.x * 128, m0 = blockIdx.y * 128;
    int wv = t >> 6, lane = t & 63, lm = lane & 15, q = lane >> 4;
    int wrow = (wv >> 1) * 64, wcol = (wv & 1) * 64;

    // staging: thread t covers LDS slot [t*16, t*16+16) => row r=t>>2, slot t&3
    // holds source chunk (t&3)^(r&3) (XOR swizzle to spread fragment-read banks)
    int r = t >> 2;
    int csrc = (t & 3) ^ (r & 3);
    const char* Ap = A + (long)(m0 + r) * K + csrc * 16;
    const char* Bp = Bw + (long)(n0 + r) * K + csrc * 16;
    long rowoff = (long)64 * K;

    v4i acc[4][4] = {};
    int aidx[4], bidx[4];
#pragma unroll
    for (int i = 0; i < 4; i++) {
        int ml = wrow + i * 16 + lm;
        aidx[i] = ml * 4 + (q ^ (ml & 3));
        int nl = wcol + i * 16 + lm;
        bidx[i] = nl * 4 + (q ^ (nl & 3));
    }

    auto issue = [&](int it, int buf) {
        long k0 = (long)it << 6;
        async_copy16(Ap + k0,          As[buf] + t * 16);
        async_copy16(Ap + rowoff + k0, As[buf] + 4096 + t * 16);
        async_copy16(Bp + k0,          Bs[buf] + t * 16);
        async_copy16(Bp + rowoff + k0, Bs[buf] + 4096 + t * 16);
    };

    int nIt = K >> 6;
    issue(0, 0);
    for (int it = 0; it < nIt; ++it) {
        int cur = it & 1;
        if (it + 1 < nIt) {
            issue(it + 1, cur ^ 1);
            asm volatile("s_waitcnt vmcnt(4)" ::: "memory");  // tile `it` landed; prefetch in flight
        } else {
            asm volatile("s_waitcnt vmcnt(0)" ::: "memory");  // peeled last tile
        }
        asm volatile("s_barrier" ::: "memory");               // all waves' copies for `it` done
        const v4i* As4 = (const v4i*)As[cur];
        const v4i* Bs4 = (const v4i*)Bs[cur];
        v4i a[4], b[4];
#pragma unroll
        for (int i = 0; i < 4; i++) { a[i] = As4[aidx[i]]; b[i] = Bs4[bidx[i]]; }
#pragma unroll
        for (int i = 0; i < 4; i++)
#pragma unroll
            for (int j = 0; j < 4; j++)
                acc[i][j] = __builtin_amdgcn_mfma_i32_16x16x64_i8(a[i], b[j], acc[i][j], 0, 0, 0);
        asm volatile("s_barrier" ::: "memory");               // reads of `cur` done before it+1 overwrites
    }

    float wsc = *wscale_p;
#pragma unroll
    for (int i = 0; i < 4; i++) {
        int mg = m0 + wrow + i * 16 + q * 4;
        float fs[4];
#pragma unroll
        for (int rr = 0; rr < 4; rr++) fs[rr] = rs[mg + rr] * wsc;
#pragma unroll
        for (int j = 0; j < 4; j++) {
            int ng = n0 + wcol + j * 16 + lm;
            float bv = bias[ng];
#pragma unroll
            for (int rr = 0; rr < 4; rr++) {
                float v = (float)acc[i][j][rr] * fs[rr] + bv;
                if (DO_GELU) v = 0.5f * v * (1.f + fast_erf(v * 0.70710678118654752f));
                long idx = (long)(mg + rr) * N + ng;
                if (OUT_F32) ((float*)outp)[idx] = v;
                else ((unsigned short*)outp)[idx] = f2bf(v);
            }
        }
    }
}

extern "C" void kernel_launch(void* const* d_in, const int* in_sizes, int n_in,
                              void* d_out, int out_size, void* d_ws, size_t ws_size,
                              hipStream_t stream) {
    const float* x  = (const float*)d_in[0];
    const float* w1 = (const float*)d_in[1];
    const float* b1 = (const float*)d_in[2];
    const float* w2 = (const float*)d_in[3];
    const float* b2 = (const float*)d_in[4];
    float* out = (float*)d_out;

    char* ws = (char*)d_ws;
    float* acc1 = (float*)(ws + 0);
    float* acc2 = (float*)(ws + 4);
    float* wsc1 = (float*)(ws + 8);
    float* wsc2 = (float*)(ws + 12);
    size_t off = 256;
    char* w1q = ws + off; off += (size_t)INNER * DIM;        // 4 MB
    char* w2q = ws + off; off += (size_t)INNER * DIM;        // 4 MB
    char* xq1 = ws + off; off += (size_t)TOK * DIM;          // 16 MB
    float* rs1 = (float*)(ws + off); off += (size_t)TOK * 4; // 64 KB
    char* xq2 = ws + off; off += (size_t)TOK * INNER;        // 64 MB
    float* rs2 = (float*)(ws + off); off += (size_t)TOK * 4; // 64 KB
    unsigned short* h = (unsigned short*)(ws + off);         // 128 MB bf16

    hipMemsetAsync(d_ws, 0, 16, stream);

    int nw = INNER * DIM;
    absmean_k<<<1024, 256, 0, stream>>>(w1, nw / 4, acc1);
    absmean_k<<<1024, 256, 0, stream>>>(w2, nw / 4, acc2);
    wquant_k<<<2048, 256, 0, stream>>>(w1, nw, acc1, wsc1, w1q);
    wquant_k<<<2048, 256, 0, stream>>>(w2, nw, acc2, wsc2, w2q);

    actquant_f32_k<DIM, 4><<<TOK, 256, 0, stream>>>(x, xq1, rs1);
    gemm_i8_k<1, 0><<<dim3(INNER / 128, TOK / 128), 256, 0, stream>>>(
        xq1, w1q, rs1, wsc1, b1, (void*)h, TOK, INNER, DIM);
    actquant_bf16_k<INNER, 16><<<TOK, 256, 0, stream>>>(h, xq2, rs2);
    gemm_i8_k<0, 1><<<dim3(DIM / 128, TOK / 128), 256, 0, stream>>>(
        xq2, w2q, rs2, wsc2, b2, (void*)out, TOK, DIM, INNER);
}

// Round 6
// 419.498 us; speedup vs baseline: 1.1213x; 1.0488x over previous
//
#include <hip/hip_runtime.h>
#include <hip/hip_bf16.h>

#define TOK   16384
#define DIM   1024
#define INNER 4096
#define EPSF  1e-5f

typedef int v4i  __attribute__((ext_vector_type(4)));
typedef int v16i __attribute__((ext_vector_type(16)));

static __device__ __forceinline__ void async_copy16(const char* g, char* l) {
    __builtin_amdgcn_global_load_lds(
        (const __attribute__((address_space(1))) unsigned int*)g,
        (__attribute__((address_space(3))) unsigned int*)l, 16, 0, 0);
}

static __device__ __forceinline__ float bf2f(unsigned short u) {
    return __uint_as_float(((unsigned)u) << 16);
}
static __device__ __forceinline__ unsigned short f2bf(float f) {
    unsigned u = __float_as_uint(f);
    return (unsigned short)((u + 0x7fffu + ((u >> 16) & 1u)) >> 16);  // RNE
}

// erf via Abramowitz-Stegun 7.1.26, |abs err| <= 1.5e-7
static __device__ __forceinline__ float fast_erf(float z) {
    float az = fabsf(z);
    float tt = __builtin_amdgcn_rcpf(1.f + 0.3275911f * az);
    float poly = ((((1.061405429f * tt - 1.453152027f) * tt + 1.421413741f) * tt
                   - 0.284496736f) * tt + 0.254829592f) * tt;
    float er = 1.f - poly * __expf(-az * az);
    return copysignf(er, z);
}

static __device__ __forceinline__ float waveSum(float v) {
#pragma unroll
    for (int o = 32; o > 0; o >>= 1) v += __shfl_down(v, o, 64);
    return v;
}
static __device__ __forceinline__ float waveMax(float v) {
#pragma unroll
    for (int o = 32; o > 0; o >>= 1) v = fmaxf(v, __shfl_down(v, o, 64));
    return v;
}

// ---- per-tensor sum(|w|) reduction (f32 in) ----
__global__ void absmean_k(const float* __restrict__ w, int n4, float* __restrict__ acc) {
    int idx = blockIdx.x * blockDim.x + threadIdx.x;
    int stride = gridDim.x * blockDim.x;
    const float4* w4 = (const float4*)w;
    float s = 0.f;
    for (int i = idx; i < n4; i += stride) {
        float4 v = w4[i];
        s += fabsf(v.x) + fabsf(v.y) + fabsf(v.z) + fabsf(v.w);
    }
    __shared__ float sp[4];
    int wv = threadIdx.x >> 6, lane = threadIdx.x & 63;
    s = waveSum(s);
    if (lane == 0) sp[wv] = s;
    __syncthreads();
    if (threadIdx.x == 0) atomicAdd(acc, sp[0] + sp[1] + sp[2] + sp[3]);
}

// ---- per-tensor ternary quantize: wq = clip(round(w/clip(mean|w|,eps)),-1,1) ----
__global__ void wquant_k(const float* __restrict__ w, int n,
                         const float* __restrict__ acc, float* __restrict__ wscale,
                         char* __restrict__ wq) {
    float mean = *acc / (float)n;
    float cl = fmaxf(mean, EPSF);
    float s = 1.f / cl;
    if (blockIdx.x == 0 && threadIdx.x == 0) *wscale = cl;  // dequant factor
    int idx = blockIdx.x * blockDim.x + threadIdx.x;
    int stride = gridDim.x * blockDim.x;
    int n4 = n >> 2;
    const float4* w4 = (const float4*)w;
    unsigned* q4 = (unsigned*)wq;
    for (int i = idx; i < n4; i += stride) {
        float4 v = w4[i];
        float e[4] = {v.x, v.y, v.z, v.w};
        unsigned packed = 0;
#pragma unroll
        for (int j = 0; j < 4; j++) {
            float r = rintf(e[j] * s);
            r = fminf(fmaxf(r, -1.f), 1.f);
            packed |= ((unsigned)((int)r & 0xff)) << (8 * j);
        }
        q4[i] = packed;
    }
}

// ---- RMSNorm + per-token absmax int8 quant, f32 input. One block per row. ----
template <int D, int VPT>
__global__ void actquant_f32_k(const float* __restrict__ X, char* __restrict__ Q,
                               float* __restrict__ rs_out) {
    int token = blockIdx.x;
    int t = threadIdx.x;
    const float4* xp = (const float4*)(X + (long)token * D);
    float vals[VPT];
    float ss = 0.f, am = 0.f;
#pragma unroll
    for (int j = 0; j < VPT / 4; j++) {
        float4 v = xp[t * (VPT / 4) + j];
        vals[4 * j] = v.x; vals[4 * j + 1] = v.y; vals[4 * j + 2] = v.z; vals[4 * j + 3] = v.w;
        ss += v.x * v.x + v.y * v.y + v.z * v.z + v.w * v.w;
        am = fmaxf(am, fmaxf(fmaxf(fabsf(v.x), fabsf(v.y)), fmaxf(fabsf(v.z), fabsf(v.w))));
    }
    __shared__ float sp[8];
    __shared__ float bc[2];
    int wv = t >> 6, lane = t & 63;
    float S = waveSum(ss);
    float M = waveMax(am);
    if (lane == 0) { sp[wv] = S; sp[4 + wv] = M; }
    __syncthreads();
    if (t == 0) {
        float Sa = sp[0] + sp[1] + sp[2] + sp[3];
        float Ma = fmaxf(fmaxf(sp[4], sp[5]), fmaxf(sp[6], sp[7]));
        float rinv = rsqrtf(Sa * (1.f / (float)D) + EPSF);   // rsqrt(mean(x^2)+eps)
        float amn = Ma * rinv;                                // absmax of normalized row
        float scale = 127.f / fmaxf(amn, EPSF);
        rs_out[token] = 1.f / scale;                          // dequant factor
        bc[0] = rinv; bc[1] = scale;
    }
    __syncthreads();
    float rinv = bc[0], scale = bc[1];
    unsigned outw[VPT / 4];
#pragma unroll
    for (int j = 0; j < VPT; j++) {
        float r = rintf((vals[j] * rinv) * scale);
        r = fminf(fmaxf(r, -128.f), 127.f);
        unsigned qi = (unsigned)((int)r & 0xff) << (8 * (j & 3));
        if ((j & 3) == 0) outw[j / 4] = qi; else outw[j / 4] |= qi;
    }
    unsigned* qp = (unsigned*)(Q + (long)token * D);
#pragma unroll
    for (int j = 0; j < VPT / 4; j++) qp[t * (VPT / 4) + j] = outw[j];
}

// ---- RMSNorm + int8 quant, bf16 input (intermediate h), uint4-vectorized. ----
template <int D, int VPT>  // VPT must be 16
__global__ void actquant_bf16_k(const unsigned short* __restrict__ X, char* __restrict__ Q,
                                float* __restrict__ rs_out) {
    int token = blockIdx.x;
    int t = threadIdx.x;
    const uint4* xp = (const uint4*)(X + (long)token * D);
    float vals[VPT];
    float ss = 0.f, am = 0.f;
#pragma unroll
    for (int j = 0; j < VPT / 8; j++) {
        uint4 v = xp[t * (VPT / 8) + j];
        unsigned ws[4] = {v.x, v.y, v.z, v.w};
#pragma unroll
        for (int p = 0; p < 4; p++) {
            float f0 = bf2f((unsigned short)(ws[p] & 0xffff));
            float f1 = bf2f((unsigned short)(ws[p] >> 16));
            vals[8 * j + 2 * p] = f0; vals[8 * j + 2 * p + 1] = f1;
            ss += f0 * f0 + f1 * f1;
            am = fmaxf(am, fmaxf(fabsf(f0), fabsf(f1)));
        }
    }
    __shared__ float sp[8];
    __shared__ float bc[2];
    int wv = t >> 6, lane = t & 63;
    float S = waveSum(ss);
    float M = waveMax(am);
    if (lane == 0) { sp[wv] = S; sp[4 + wv] = M; }
    __syncthreads();
    if (t == 0) {
        float Sa = sp[0] + sp[1] + sp[2] + sp[3];
        float Ma = fmaxf(fmaxf(sp[4], sp[5]), fmaxf(sp[6], sp[7]));
        float rinv = rsqrtf(Sa * (1.f / (float)D) + EPSF);
        float amn = Ma * rinv;
        float scale = 127.f / fmaxf(amn, EPSF);
        rs_out[token] = 1.f / scale;
        bc[0] = rinv; bc[1] = scale;
    }
    __syncthreads();
    float rinv = bc[0], scale = bc[1];
    unsigned outw[4];
#pragma unroll
    for (int j = 0; j < VPT; j++) {
        float r = rintf((vals[j] * rinv) * scale);
        r = fminf(fmaxf(r, -128.f), 127.f);
        unsigned qi = (unsigned)((int)r & 0xff) << (8 * (j & 3));
        if ((j & 3) == 0) outw[j / 4] = qi; else outw[j / 4] |= qi;
    }
    uint4* qp = (uint4*)(Q + (long)token * D);
    qp[t] = make_uint4(outw[0], outw[1], outw[2], outw[3]);
}

// ---- int8 GEMM: 256x128 tile, BK=64, wave tile 128x64 via mfma_i32_32x32x32_i8 ----
// 85 ops/LDS-byte (vs 64 for 64x64 wave tile) -> LDS/MFMA balanced.
// Double-buffered global_load_lds(16B) with fine vmcnt(6); swizzle (row>>1)&3 spreads
// 32-row fragment reads over all 8 LDS bank-groups.
// C[m,n] = sum_k A[m,k]*W[n,k]; epilogue: *rs[m]*wsc + bias[n]; opt fast-erf GELU.
template <int DO_GELU, int OUT_F32>
__global__ __launch_bounds__(256, 2) void gemm_i8_k(
    const char* __restrict__ A, const char* __restrict__ Bw,
    const float* __restrict__ rs, const float* __restrict__ wscale_p,
    const float* __restrict__ bias, void* __restrict__ outp,
    int M, int N, int K) {
    __shared__ char As[2][16384];   // 256 rows x 64B
    __shared__ char Bs[2][8192];    // 128 rows x 64B
    int t = threadIdx.x;
    int n0 = blockIdx.x * 128, m0 = blockIdx.y * 256;
    int wv = t >> 6, lane = t & 63;
    int l31 = lane & 31, kh = lane >> 5;          // kh: 16B half along K within a 32B k-step
    int wm = (wv & 1) * 128, wn = (wv >> 1) * 64; // wave tile origin

    // staging: copy op c covers rows c*64 + (t>>2); LDS slot t&3 of that row holds
    // source chunk (t&3) ^ ((row>>1)&3)
    int r = t >> 2;
    const char* aps[4];
    const char* bps[2];
#pragma unroll
    for (int c = 0; c < 4; c++) {
        int row = c * 64 + r;
        int src = (t & 3) ^ ((row >> 1) & 3);
        aps[c] = A + (long)(m0 + row) * K + src * 16;
    }
#pragma unroll
    for (int c = 0; c < 2; c++) {
        int row = c * 64 + r;
        int src = (t & 3) ^ ((row >> 1) & 3);
        bps[c] = Bw + (long)(n0 + row) * K + src * 16;
    }

    v16i acc[4][2] = {};
    int aidx[4][2], bidx[2][2];
#pragma unroll
    for (int i = 0; i < 4; i++) {
        int row = wm + i * 32 + l31;
        int sw = (row >> 1) & 3;
#pragma unroll
        for (int ks = 0; ks < 2; ks++) aidx[i][ks] = row * 4 + ((ks * 2 + kh) ^ sw);
    }
#pragma unroll
    for (int j = 0; j < 2; j++) {
        int row = wn + j * 32 + l31;
        int sw = (row >> 1) & 3;
#pragma unroll
        for (int ks = 0; ks < 2; ks++) bidx[j][ks] = row * 4 + ((ks * 2 + kh) ^ sw);
    }

    auto issue = [&](int it, int buf) {
        long k0 = (long)it << 6;
#pragma unroll
        for (int c = 0; c < 4; c++) async_copy16(aps[c] + k0, As[buf] + c * 4096 + t * 16);
#pragma unroll
        for (int c = 0; c < 2; c++) async_copy16(bps[c] + k0, Bs[buf] + c * 4096 + t * 16);
    };

    int nIt = K >> 6;
    issue(0, 0);
    for (int it = 0; it < nIt; ++it) {
        int cur = it & 1;
        if (it + 1 < nIt) {
            issue(it + 1, cur ^ 1);
            asm volatile("s_waitcnt vmcnt(6)" ::: "memory");  // tile `it` landed; prefetch in flight
        } else {
            asm volatile("s_waitcnt vmcnt(0)" ::: "memory");
        }
        asm volatile("s_barrier" ::: "memory");
        const v4i* As4 = (const v4i*)As[cur];
        const v4i* Bs4 = (const v4i*)Bs[cur];
#pragma unroll
        for (int ks = 0; ks < 2; ks++) {
            v4i a[4], b[2];
#pragma unroll
            for (int i = 0; i < 4; i++) a[i] = As4[aidx[i][ks]];
#pragma unroll
            for (int j = 0; j < 2; j++) b[j] = Bs4[bidx[j][ks]];
#pragma unroll
            for (int i = 0; i < 4; i++)
#pragma unroll
                for (int j = 0; j < 2; j++)
                    acc[i][j] = __builtin_amdgcn_mfma_i32_32x32x32_i8(a[i], b[j], acc[i][j], 0, 0, 0);
        }
        asm volatile("s_barrier" ::: "memory");  // reads done before it+1 DMA reuses this buf
    }

    // Epilogue. 32x32 C/D layout: col = lane&31, row = (reg&3) + 8*(reg>>2) + 4*(lane>>5)
    float wsc = *wscale_p;
    float bv[2];
#pragma unroll
    for (int j = 0; j < 2; j++) bv[j] = bias[n0 + wn + j * 32 + l31];
#pragma unroll
    for (int i = 0; i < 4; i++) {
        int mbase = m0 + wm + i * 32 + 4 * kh;
        float fsv[16];
#pragma unroll
        for (int rg = 0; rg < 16; rg++)
            fsv[rg] = rs[mbase + (rg & 3) + 8 * (rg >> 2)] * wsc;
#pragma unroll
        for (int j = 0; j < 2; j++) {
            int ng = n0 + wn + j * 32 + l31;
#pragma unroll
            for (int rg = 0; rg < 16; rg++) {
                int mg = mbase + (rg & 3) + 8 * (rg >> 2);
                float v = (float)acc[i][j][rg] * fsv[rg] + bv[j];
                if (DO_GELU) v = 0.5f * v * (1.f + fast_erf(v * 0.70710678118654752f));
                long idx = (long)mg * N + ng;
                if (OUT_F32) ((float*)outp)[idx] = v;
                else ((unsigned short*)outp)[idx] = f2bf(v);
            }
        }
    }
}

extern "C" void kernel_launch(void* const* d_in, const int* in_sizes, int n_in,
                              void* d_out, int out_size, void* d_ws, size_t ws_size,
                              hipStream_t stream) {
    const float* x  = (const float*)d_in[0];
    const float* w1 = (const float*)d_in[1];
    const float* b1 = (const float*)d_in[2];
    const float* w2 = (const float*)d_in[3];
    const float* b2 = (const float*)d_in[4];
    float* out = (float*)d_out;

    char* ws = (char*)d_ws;
    float* acc1 = (float*)(ws + 0);
    float* acc2 = (float*)(ws + 4);
    float* wsc1 = (float*)(ws + 8);
    float* wsc2 = (float*)(ws + 12);
    size_t off = 256;
    char* w1q = ws + off; off += (size_t)INNER * DIM;        // 4 MB
    char* w2q = ws + off; off += (size_t)INNER * DIM;        // 4 MB
    char* xq1 = ws + off; off += (size_t)TOK * DIM;          // 16 MB
    float* rs1 = (float*)(ws + off); off += (size_t)TOK * 4; // 64 KB
    char* xq2 = ws + off; off += (size_t)TOK * INNER;        // 64 MB
    float* rs2 = (float*)(ws + off); off += (size_t)TOK * 4; // 64 KB
    unsigned short* h = (unsigned short*)(ws + off);         // 128 MB bf16

    hipMemsetAsync(d_ws, 0, 16, stream);

    int nw = INNER * DIM;
    absmean_k<<<1024, 256, 0, stream>>>(w1, nw / 4, acc1);
    absmean_k<<<1024, 256, 0, stream>>>(w2, nw / 4, acc2);
    wquant_k<<<2048, 256, 0, stream>>>(w1, nw, acc1, wsc1, w1q);
    wquant_k<<<2048, 256, 0, stream>>>(w2, nw, acc2, wsc2, w2q);

    actquant_f32_k<DIM, 4><<<TOK, 256, 0, stream>>>(x, xq1, rs1);
    gemm_i8_k<1, 0><<<dim3(INNER / 128, TOK / 256), 256, 0, stream>>>(
        xq1, w1q, rs1, wsc1, b1, (void*)h, TOK, INNER, DIM);
    actquant_bf16_k<INNER, 16><<<TOK, 256, 0, stream>>>(h, xq2, rs2);
    gemm_i8_k<0, 1><<<dim3(DIM / 128, TOK / 256), 256, 0, stream>>>(
        xq2, w2q, rs2, wsc2, b2, (void*)out, TOK, DIM, INNER);
}